// Round 11
// baseline (53.578 us; speedup 1.0000x reference)
//
#include <hip/hip_runtime.h>
#include <math.h>

#define NCH 384
#define RNK 5
#define NA  32
#define NSTART 384            // starts < NCH-NA+1 = 353; 384 bins for safety
#define NREP 8                // counter/sub-list replicas per bucket
#define CAPR 128              // slots per (bucket, replica) sub-list
#define CAP (NREP*CAPR)       // 1024 slots per bucket
#define GRID 1536             // 6 blocks/CU x 256 CU
#define NTILES (NSTART*NREP)  // 1 tile per (bucket, sub-list): 3072
#define TILE_W 192            // 160 numerator + 32 nan-weight partials
#define EMP_GRID ((RNK*NCH + 3) / 4)   // 480 blocks, 1 wave per output elem
#define FLT_BIG 3.402823466e38f

// ---- ws word layout ----
#define WS_CUR   0                         // NSTART*NREP u32 fill counters
#define WS_TOTP  (WS_CUR + NSTART*NREP)    // GRID f32 partial totals
#define WS_MINP  (WS_TOTP + GRID)          // GRID f32 partial mins
#define WS_ORDER (WS_MINP + GRID)          // NSTART*CAP u32
#define WS_TILE  (WS_ORDER + NSTART*CAP)   // NTILES*TILE_W f32
#define WS_WORDS (WS_TILE + NTILES*TILE_W)

__device__ __forceinline__ bool finitef(float v) {
    return fabsf(v) <= FLT_BIG;   // NaN fails, +-inf exceeds
}

// ---- k1: zero counters + lik-min partials (no cg::grid.sync: R9 measured
// ~150us/sync on MI355X; stream ordering is the barrier) ----
__global__ __launch_bounds__(256) void k_init(
    const float* __restrict__ lik_data, int nnz,
    unsigned* __restrict__ wsu, float* __restrict__ wsf)
{
    const int tid = threadIdx.x, bid = blockIdx.x;
    const int lane = tid & 63, wave = tid >> 6;
    int i = bid * 256 + tid;
    if (i < NSTART * NREP) wsu[WS_CUR + i] = 0u;

    float m = FLT_BIG;
    const int G = GRID * 256;
    const int n4 = nnz >> 2;
    const float4* d4 = (const float4*)lik_data;
    for (int j = bid * 256 + tid; j < n4; j += G) {
        float4 v = d4[j];
        m = fminf(m, fminf(fminf(v.x, v.y), fminf(v.z, v.w)));
    }
    for (int j = (n4 << 2) + bid * 256 + tid; j < nnz; j += G)
        m = fminf(m, lik_data[j]);

    #pragma unroll
    for (int o = 32; o; o >>= 1) m = fminf(m, __shfl_down(m, o));
    __shared__ float sm[4];
    if (lane == 0) sm[wave] = m;
    __syncthreads();
    if (tid == 0)      // plain store to private slot — no funnel
        wsf[WS_MINP + bid] = fminf(fminf(sm[0], sm[1]), fminf(sm[2], sm[3]));
}

// ---- k2: min fold + bucket scatter + weight totals + ASSIGNMENTS ----
// (assignment argmax is independent of the emp_mean chain; doing it here
// overlaps its streaming loads with the scatter's atomic latency)
__global__ __launch_bounds__(256) void k_prep(
    const int* __restrict__ channels, const float* __restrict__ weights,
    const int* __restrict__ lik_rows, const float* __restrict__ lik_data,
    int n, int per, unsigned* __restrict__ wsu, float* __restrict__ wsf,
    float* __restrict__ out)
{
    const int tid = threadIdx.x, bid = blockIdx.x;
    const int lane = tid & 63, wave = tid >> 6;
    const int rep = bid & (NREP - 1);
    const int G = GRID * 256;

    // fold k1's min partials (6KB, L2-broadcast; same order in every block)
    float m = FLT_BIG;
    for (int i = tid; i < GRID; i += 256) m = fminf(m, wsf[WS_MINP + i]);
    #pragma unroll
    for (int o = 32; o; o >>= 1) m = fminf(m, __shfl_down(m, o));
    __shared__ float sm[4];
    if (lane == 0) sm[wave] = m;
    __syncthreads();
    const float offset =
        fminf(fminf(sm[0], sm[1]), fminf(sm[2], sm[3])) - 1.0f;

    // scatter + per-block weight total
    float tw = 0.f;
    for (int sp = bid * 256 + tid; sp < n; sp += G) {
        const int st = channels[(size_t)sp * NA];   // channels[sp][0] == start
        unsigned pos = atomicAdd(&wsu[WS_CUR + st * NREP + rep], 1u);
        if (pos < CAPR)
            wsu[WS_ORDER + (size_t)st * CAP + rep * CAPR + pos] = (unsigned)sp;
        tw += weights[sp];
    }
    #pragma unroll
    for (int o = 32; o; o >>= 1) tw += __shfl_down(tw, o);
    __shared__ float st4[4];
    if (lane == 0) st4[wave] = tw;
    __syncthreads();
    if (tid == 0)      // plain store to private slot — no funnel
        wsf[WS_TOTP + bid] = st4[0] + st4[1] + st4[2] + st4[3];

    // assignments: grid-stride argmax with min-row tie-break
    for (int sp = bid * 256 + tid; sp < n; sp += G) {
        const float* d  = lik_data + (size_t)sp * per;
        const int*   rr = lik_rows + (size_t)sp * per;
        float bs = -FLT_BIG;
        int br = 0x7FFFFFFF;
        for (int j = 0; j < per; ++j) {
            float s = d[j] - offset;    // same f32 op as reference's `shifted`
            int r = rr[j];
            if (s > bs) { bs = s; br = r; }
            else if (s == bs && r < br) br = r;
        }
        out[RNK * NCH + sp] = (float)br;
    }
}

// ---- k3: bucketed accumulation -> private partial tiles ----
// block bid: bucket b = bid>>3, sub-list rep = bid&7 (3072 blocks, 8/CU).
// lane owns tile elems {lane, lane+64} (+ lane+128 for lane<32); e = r*32+a.
__global__ __launch_bounds__(256, 8) void k_accum(
    const float* __restrict__ feats, const float* __restrict__ weights,
    const unsigned* __restrict__ wsu, float* __restrict__ wsf)
{
    __shared__ float s_tile[TILE_W];
    const int bid = blockIdx.x, tid = threadIdx.x;
    const int b = bid >> 3, rep = bid & 7;
    const int lane = tid & 63, wave = tid >> 6;

    for (int i = tid; i < TILE_W; i += 256) s_tile[i] = 0.f;
    __syncthreads();

    int cnt = (int)wsu[WS_CUR + b * NREP + rep];
    if (cnt > CAPR) cnt = CAPR;
    const unsigned* order = wsu + WS_ORDER + (size_t)b * CAP + rep * CAPR;

    float acc0 = 0.f, acc1 = 0.f, acc2 = 0.f, nanw = 0.f;
    int spike = 0; float w = 0.f;
    if (wave < cnt) { spike = (int)order[wave]; w = weights[spike]; }
    for (int k = wave; k < cnt; k += 4) {
        const float* f = feats + (size_t)spike * (RNK * NA);
        int ns = 0; float nw = 0.f;
        if (k + 4 < cnt) {               // prefetch next (spike, weight)
            ns = (int)order[k + 4];
            nw = weights[ns];
        }
        const float v0 = f[lane];          // elems [0,64)   ranks 0-1
        const float v1 = f[lane + 64];     // elems [64,128) ranks 2-3
        const float v2 = (lane < 32) ? f[lane + 128] : 0.f;  // rank 4
        const float r0 = __shfl(v0, lane & 31);  // rank-0 of column a
        if (finitef(r0)) {
            acc0 += w * (finitef(v0) ? v0 : 0.f);
            acc1 += w * (finitef(v1) ? v1 : 0.f);
            if (lane < 32) acc2 += w * (finitef(v2) ? v2 : 0.f);
        } else if (lane < 32) {
            nanw += w;
        }
        spike = ns; w = nw;
    }

    atomicAdd(&s_tile[lane], acc0);
    atomicAdd(&s_tile[64 + lane], acc1);
    if (lane < 32) {
        atomicAdd(&s_tile[128 + lane], acc2);
        atomicAdd(&s_tile[160 + lane], nanw);
    }
    __syncthreads();

    float* dst = wsf + WS_TILE + (size_t)bid * TILE_W;  // private: plain stores
    for (int i = tid; i < TILE_W; i += 256) dst[i] = s_tile[i];
}

// ---- k4: tot fold + emp_mean gather (tiny: 480 blocks) ----
__global__ __launch_bounds__(256) void k_final(
    float* __restrict__ wsf, float* __restrict__ out)
{
    const int tid = threadIdx.x, bid = blockIdx.x;
    const int lane = tid & 63, wave = tid >> 6;

    float t = 0.f;
    for (int i = tid; i < GRID; i += 256) t += wsf[WS_TOTP + i];
    #pragma unroll
    for (int o = 32; o; o >>= 1) t += __shfl_down(t, o);
    __shared__ float st4[4];
    if (lane == 0) st4[wave] = t;
    __syncthreads();
    const float tot = st4[0] + st4[1] + st4[2] + st4[3];

    // one wave per output element; lanes split (db, tile-half of 8 slots)
    const int wg = bid * 4 + wave;
    if (wg < RNK * NCH) {
        const int c = wg % NCH, r = wg / NCH;
        const int db = lane & 31, half = lane >> 5;
        float s = 0.f, nb = 0.f;
        const int b = c - db;
        if (b >= 0) {
            #pragma unroll
            for (int jj = 0; jj < 4; ++jj) {
                const float* tp =
                    wsf + WS_TILE + ((size_t)b * NREP + jj * 2 + half) * TILE_W;
                s  += tp[r * 32 + db];
                nb += tp[160 + db];
            }
        }
        #pragma unroll
        for (int o = 32; o; o >>= 1) {
            s  += __shfl_down(s, o);
            nb += __shfl_down(nb, o);
        }
        if (lane == 0) out[wg] = s / (tot - nb);
    }
}

// ================= minimal-ws fallback (verified R2 lineage) ================
#define FB_NUM   0
#define FB_NANW  (RNK*NCH)
#define FB_TOT   (FB_NANW + NCH)
#define FB_MIN   (FB_TOT + 1)
#define FB_WORDS (FB_MIN + 1)

__device__ __forceinline__ unsigned fenc(float f) {
    unsigned u = __float_as_uint(f);
    return (u & 0x80000000u) ? ~u : (u | 0x80000000u);
}
__device__ __forceinline__ float fdec(unsigned u) {
    unsigned b = (u & 0x80000000u) ? (u ^ 0x80000000u) : ~u;
    return __uint_as_float(b);
}
__global__ void fb_init_kernel(unsigned* ws) {
    int i = blockIdx.x * blockDim.x + threadIdx.x;
    if (i < FB_WORDS) ws[i] = (i == FB_MIN) ? 0xFFFFFFFFu : 0u;
}
__global__ __launch_bounds__(256) void fb_accum_kernel(
    const float* feats, const int* channels, const float* weights,
    float* ws, int n)
{
    __shared__ float s_num[RNK * NCH];
    __shared__ float s_nanw[NCH];
    __shared__ float s_total;
    const int tid = threadIdx.x;
    for (int i = tid; i < RNK * NCH; i += 256) s_num[i] = 0.f;
    for (int i = tid; i < NCH; i += 256) s_nanw[i] = 0.f;
    if (tid == 0) s_total = 0.f;
    __syncthreads();
    const int total = n * NA;
    const int stride = gridDim.x * blockDim.x;
    float tw = 0.f;
    for (int idx = blockIdx.x * blockDim.x + tid; idx < total; idx += stride) {
        const int spike = idx >> 5, a = idx & (NA - 1);
        const int ch = channels[idx];
        const float w = weights[spike];
        if (a == 0) tw += w;
        const float* f = feats + (size_t)spike * (RNK * NA) + a;
        const float v0 = f[0];
        if (finitef(v0)) {
            atomicAdd(&s_num[ch], w * v0);
            #pragma unroll
            for (int r = 1; r < RNK; ++r) {
                float v = f[r * NA];
                if (!finitef(v)) v = 0.f;
                atomicAdd(&s_num[r * NCH + ch], w * v);
            }
        } else atomicAdd(&s_nanw[ch], w);
    }
    #pragma unroll
    for (int off = 32; off; off >>= 1) tw += __shfl_down(tw, off);
    if ((tid & 63) == 0) atomicAdd(&s_total, tw);
    __syncthreads();
    for (int i = tid; i < RNK * NCH; i += 256)
        if (s_num[i] != 0.f) atomicAdd(&ws[FB_NUM + i], s_num[i]);
    for (int i = tid; i < NCH; i += 256)
        if (s_nanw[i] != 0.f) atomicAdd(&ws[FB_NANW + i], s_nanw[i]);
    if (tid == 0) atomicAdd(&ws[FB_TOT], s_total);
}
__global__ void fb_min_kernel(const float* data, int nnz, unsigned* minw) {
    float m = FLT_BIG;
    for (int i = blockIdx.x * blockDim.x + threadIdx.x; i < nnz;
         i += gridDim.x * blockDim.x) m = fminf(m, data[i]);
    #pragma unroll
    for (int off = 32; off; off >>= 1) m = fminf(m, __shfl_down(m, off));
    if ((threadIdx.x & 63) == 0) atomicMin(minw, fenc(m));
}
__global__ void fb_finalize_kernel(const float* ws, float* out) {
    int i = blockIdx.x * blockDim.x + threadIdx.x;
    if (i < RNK * NCH) {
        int c = i % NCH;
        float cnt = ws[FB_TOT] - ws[FB_NANW + c];
        out[i] = ws[FB_NUM + i] / cnt;
    }
}
__global__ __launch_bounds__(256) void fb_assign_kernel(
    const int* rows, const float* data, const unsigned* minw,
    float* out, int n, int per)
{
    const int spike = blockIdx.x * 256 + threadIdx.x;
    if (spike >= n) return;
    const float offset = fdec(*minw) - 1.0f;
    const float* d  = data + (size_t)spike * per;
    const int*   rr = rows + (size_t)spike * per;
    float bs = -FLT_BIG;
    int br = 0x7FFFFFFF;
    for (int j = 0; j < per; ++j) {
        float s = d[j] - offset;
        int r = rr[j];
        if (s > bs) { bs = s; br = r; }
        else if (s == bs && r < br) br = r;
    }
    out[RNK * NCH + spike] = (float)br;
}

// ================= host ======================================================
extern "C" void kernel_launch(void* const* d_in, const int* in_sizes, int n_in,
                              void* d_out, int out_size, void* d_ws, size_t ws_size,
                              hipStream_t stream) {
    const float* feats    = (const float*)d_in[0];
    const int*   channels = (const int*)d_in[1];
    const float* weights  = (const float*)d_in[2];
    const int*   lik_rows = (const int*)d_in[3];
    const float* lik_data = (const float*)d_in[5];

    int n   = in_sizes[2];
    int nnz = in_sizes[3];
    int per = nnz / n;

    float*    out = (float*)d_out;
    unsigned* wsu = (unsigned*)d_ws;
    float*    wsf = (float*)d_ws;

    const size_t req_bytes = (size_t)WS_WORDS * 4;
    // per-(bucket,rep) sub-list overflow margin (avg fill ~21 of 128)
    const bool cap_ok = (n <= NSTART * NREP * CAPR / 4);

    if (ws_size >= req_bytes && cap_ok) {
        k_init<<<GRID, 256, 0, stream>>>(lik_data, nnz, wsu, wsf);
        k_prep<<<GRID, 256, 0, stream>>>(channels, weights, lik_rows, lik_data,
                                         n, per, wsu, wsf, out);
        k_accum<<<NSTART * NREP, 256, 0, stream>>>(feats, weights, wsu, wsf);
        k_final<<<EMP_GRID, 256, 0, stream>>>(wsf, out);
    } else {
        fb_init_kernel<<<(FB_WORDS + 255) / 256, 256, 0, stream>>>(wsu);
        fb_accum_kernel<<<1024, 256, 0, stream>>>(feats, channels, weights, wsf, n);
        fb_finalize_kernel<<<(RNK * NCH + 255) / 256, 256, 0, stream>>>(wsf, out);
        fb_min_kernel<<<256, 256, 0, stream>>>(lik_data, nnz, wsu + FB_MIN);
        fb_assign_kernel<<<(n + 255) / 256, 256, 0, stream>>>(
            lik_rows, lik_data, wsu + FB_MIN, out, n, per);
    }
}

// Round 12
// 42.414 us; speedup vs baseline: 1.2632x; 1.2632x over previous
//
#include <hip/hip_runtime.h>
#include <math.h>

#define NCH 384
#define RNK 5
#define NA  32
#define NSTART 384            // starts < NCH-NA+1 = 353; 384 bins for safety
#define NREP 8                // counter/sub-list replicas per bucket
#define CAPR 128              // slots per (bucket, replica) sub-list
#define CAP (NREP*CAPR)       // 1024 slots per bucket
#define GRID 1536             // 6 blocks/CU x 256 CU
#define NTILES (NSTART*4)     // 4 tiles per bucket (accum block eats 2 sub-lists)
#define TILE_W 192            // 160 numerator + 32 nan-weight partials
#define FLT_BIG 3.402823466e38f

// ---- ws word layout ----
#define WS_CUR   0                           // NSTART*NREP u32 fill counters
#define WS_TOTP  (WS_CUR + NSTART*NREP)      // GRID f32 partial totals
#define WS_MINP  (WS_TOTP + GRID)            // GRID f32 partial mins
#define WS_ORDER (WS_MINP + GRID)            // NSTART*CAP uint2 (packed spike,weight)
#define WS_TILE  (WS_ORDER + NSTART*CAP*2)   // NTILES*TILE_W f32
#define WS_WORDS (WS_TILE + NTILES*TILE_W)

__device__ __forceinline__ bool finitef(float v) {
    return fabsf(v) <= FLT_BIG;   // NaN fails, +-inf exceeds
}

// ---- k1: zero counters + lik-min partials (no cg::grid.sync: R9 measured
// ~150us/sync on MI355X; stream ordering is the barrier) ----
__global__ __launch_bounds__(256) void k_init(
    const float* __restrict__ lik_data, int nnz,
    unsigned* __restrict__ wsu, float* __restrict__ wsf)
{
    const int tid = threadIdx.x, bid = blockIdx.x;
    const int lane = tid & 63, wave = tid >> 6;
    int i = bid * 256 + tid;
    if (i < NSTART * NREP) wsu[WS_CUR + i] = 0u;

    float m = FLT_BIG;
    const int G = GRID * 256;
    const int n4 = nnz >> 2;
    const float4* d4 = (const float4*)lik_data;
    for (int j = bid * 256 + tid; j < n4; j += G) {
        float4 v = d4[j];
        m = fminf(m, fminf(fminf(v.x, v.y), fminf(v.z, v.w)));
    }
    for (int j = (n4 << 2) + bid * 256 + tid; j < nnz; j += G)
        m = fminf(m, lik_data[j]);

    #pragma unroll
    for (int o = 32; o; o >>= 1) m = fminf(m, __shfl_down(m, o));
    __shared__ float sm[4];
    if (lane == 0) sm[wave] = m;
    __syncthreads();
    if (tid == 0)      // plain store to private slot — no funnel
        wsf[WS_MINP + bid] = fminf(fminf(sm[0], sm[1]), fminf(sm[2], sm[3]));
}

// ---- k2: replicated bucket scatter (packed spike+weight) + weight totals ----
__global__ __launch_bounds__(256) void k_prep(
    const int* __restrict__ channels, const float* __restrict__ weights,
    int n, unsigned* __restrict__ wsu, float* __restrict__ wsf)
{
    const int tid = threadIdx.x, bid = blockIdx.x;
    const int lane = tid & 63, wave = tid >> 6;
    const int rep = bid & (NREP - 1);
    const int G = GRID * 256;
    uint2* order = (uint2*)(wsu + WS_ORDER);

    float tw = 0.f;
    for (int sp = bid * 256 + tid; sp < n; sp += G) {
        const int st = channels[(size_t)sp * NA];   // channels[sp][0] == start
        const float wv = weights[sp];
        unsigned pos = atomicAdd(&wsu[WS_CUR + st * NREP + rep], 1u);
        if (pos < CAPR)   // pack weight with index: kills accum's dependent load
            order[(size_t)st * CAP + rep * CAPR + pos] =
                make_uint2((unsigned)sp, __float_as_uint(wv));
        tw += wv;
    }

    #pragma unroll
    for (int o = 32; o; o >>= 1) tw += __shfl_down(tw, o);
    __shared__ float st4[4];
    if (lane == 0) st4[wave] = tw;
    __syncthreads();
    if (tid == 0)      // plain store to private slot — no funnel
        wsf[WS_TOTP + bid] = st4[0] + st4[1] + st4[2] + st4[3];
}

// ---- k3: bucketed accumulation -> private partial tiles ----
// block bid: bucket b = bid>>2, tile tj = bid&3, eats sub-lists 2tj, 2tj+1.
// lane owns tile elems {lane, lane+64} (+ lane+128 for lane<32); e = r*32+a.
__global__ __launch_bounds__(256) void k_accum(
    const float* __restrict__ feats, const unsigned* __restrict__ wsu,
    float* __restrict__ wsf)
{
    __shared__ float s_tile[TILE_W];
    const int bid = blockIdx.x, tid = threadIdx.x;
    const int b = bid >> 2, tj = bid & 3;
    const int lane = tid & 63, wave = tid >> 6;

    for (int i = tid; i < TILE_W; i += 256) s_tile[i] = 0.f;
    __syncthreads();

    float acc0 = 0.f, acc1 = 0.f, acc2 = 0.f, nanw = 0.f;
    #pragma unroll
    for (int seg = 0; seg < 2; ++seg) {
        const int rep = tj * 2 + seg;
        int cnt = (int)wsu[WS_CUR + b * NREP + rep];
        if (cnt > CAPR) cnt = CAPR;
        const uint2* order =
            (const uint2*)(wsu + WS_ORDER) + (size_t)b * CAP + rep * CAPR;
        uint2 e = make_uint2(0u, 0u);
        if (wave < cnt) e = order[wave];
        for (int k = wave; k < cnt; k += 4) {
            const int spike = (int)e.x;
            const float w = __uint_as_float(e.y);
            const float* f = feats + (size_t)spike * (RNK * NA);
            uint2 ne = make_uint2(0u, 0u);
            if (k + 4 < cnt) ne = order[k + 4];   // prefetch next entry (8B)
            const float v0 = f[lane];          // elems [0,64)   ranks 0-1
            const float v1 = f[lane + 64];     // elems [64,128) ranks 2-3
            const float v2 = (lane < 32) ? f[lane + 128] : 0.f;  // rank 4
            const float r0 = __shfl(v0, lane & 31);  // rank-0 of column a
            if (finitef(r0)) {
                acc0 += w * (finitef(v0) ? v0 : 0.f);
                acc1 += w * (finitef(v1) ? v1 : 0.f);
                if (lane < 32) acc2 += w * (finitef(v2) ? v2 : 0.f);
            } else if (lane < 32) {
                nanw += w;
            }
            e = ne;
        }
    }

    atomicAdd(&s_tile[lane], acc0);
    atomicAdd(&s_tile[64 + lane], acc1);
    if (lane < 32) {
        atomicAdd(&s_tile[128 + lane], acc2);
        atomicAdd(&s_tile[160 + lane], nanw);
    }
    __syncthreads();

    float* dst = wsf + WS_TILE + (size_t)bid * TILE_W;  // private: plain stores
    for (int i = tid; i < TILE_W; i += 256) dst[i] = s_tile[i];
}

// ---- k4: partial-reduce + assignments + emp_mean gather ----
__global__ __launch_bounds__(256) void k_final(
    const int* __restrict__ lik_rows, const float* __restrict__ lik_data,
    float* __restrict__ wsf, float* __restrict__ out, int n, int per)
{
    const int tid = threadIdx.x, bid = blockIdx.x;
    const int lane = tid & 63, wave = tid >> 6;
    const bool emp_block = (bid * 4 < RNK * NCH);

    // local reduce of the GRID partials (identical order in every block ->
    // identical fp value; L2-resident). tot only needed by emp blocks.
    float m = FLT_BIG, t = 0.f;
    if (emp_block) {
        for (int i = tid; i < GRID; i += 256) {
            m = fminf(m, wsf[WS_MINP + i]);
            t += wsf[WS_TOTP + i];
        }
    } else {
        for (int i = tid; i < GRID; i += 256)
            m = fminf(m, wsf[WS_MINP + i]);
    }
    #pragma unroll
    for (int o = 32; o; o >>= 1) {
        m = fminf(m, __shfl_down(m, o));
        t += __shfl_down(t, o);
    }
    __shared__ float sm[4], st4[4];
    if (lane == 0) { sm[wave] = m; st4[wave] = t; }
    __syncthreads();
    const float mn  = fminf(fminf(sm[0], sm[1]), fminf(sm[2], sm[3]));
    const float tot = st4[0] + st4[1] + st4[2] + st4[3];

    // assignments: grid-stride, argmax with min-row tie-break
    const float offset = mn - 1.0f;
    const int G = gridDim.x * 256;
    for (int sp = bid * 256 + tid; sp < n; sp += G) {
        const float* d  = lik_data + (size_t)sp * per;
        const int*   rr = lik_rows + (size_t)sp * per;
        float bs = -FLT_BIG;
        int br = 0x7FFFFFFF;
        for (int j = 0; j < per; ++j) {
            float s = d[j] - offset;    // same f32 op as reference's `shifted`
            int r = rr[j];
            if (s > bs) { bs = s; br = r; }
            else if (s == bs && r < br) br = r;
        }
        out[RNK * NCH + sp] = (float)br;
    }

    // emp_mean: one wave per output element; lanes split (db, tile-half)
    const int wg = bid * 4 + wave;
    if (wg < RNK * NCH) {
        const int c = wg % NCH, r = wg / NCH;
        const int db = lane & 31, half = lane >> 5;
        float s = 0.f, nb = 0.f;
        const int b = c - db;
        if (b >= 0) {
            #pragma unroll
            for (int jj = 0; jj < 2; ++jj) {
                const float* tp =
                    wsf + WS_TILE + ((size_t)b * 4 + jj * 2 + half) * TILE_W;
                s  += tp[r * 32 + db];
                nb += tp[160 + db];
            }
        }
        #pragma unroll
        for (int o = 32; o; o >>= 1) {
            s  += __shfl_down(s, o);
            nb += __shfl_down(nb, o);
        }
        if (lane == 0) out[wg] = s / (tot - nb);
    }
}

// ================= minimal-ws fallback (verified R2 lineage) ================
#define FB_NUM   0
#define FB_NANW  (RNK*NCH)
#define FB_TOT   (FB_NANW + NCH)
#define FB_MIN   (FB_TOT + 1)
#define FB_WORDS (FB_MIN + 1)

__device__ __forceinline__ unsigned fenc(float f) {
    unsigned u = __float_as_uint(f);
    return (u & 0x80000000u) ? ~u : (u | 0x80000000u);
}
__device__ __forceinline__ float fdec(unsigned u) {
    unsigned b = (u & 0x80000000u) ? (u ^ 0x80000000u) : ~u;
    return __uint_as_float(b);
}
__global__ void fb_init_kernel(unsigned* ws) {
    int i = blockIdx.x * blockDim.x + threadIdx.x;
    if (i < FB_WORDS) ws[i] = (i == FB_MIN) ? 0xFFFFFFFFu : 0u;
}
__global__ __launch_bounds__(256) void fb_accum_kernel(
    const float* feats, const int* channels, const float* weights,
    float* ws, int n)
{
    __shared__ float s_num[RNK * NCH];
    __shared__ float s_nanw[NCH];
    __shared__ float s_total;
    const int tid = threadIdx.x;
    for (int i = tid; i < RNK * NCH; i += 256) s_num[i] = 0.f;
    for (int i = tid; i < NCH; i += 256) s_nanw[i] = 0.f;
    if (tid == 0) s_total = 0.f;
    __syncthreads();
    const int total = n * NA;
    const int stride = gridDim.x * blockDim.x;
    float tw = 0.f;
    for (int idx = blockIdx.x * blockDim.x + tid; idx < total; idx += stride) {
        const int spike = idx >> 5, a = idx & (NA - 1);
        const int ch = channels[idx];
        const float w = weights[spike];
        if (a == 0) tw += w;
        const float* f = feats + (size_t)spike * (RNK * NA) + a;
        const float v0 = f[0];
        if (finitef(v0)) {
            atomicAdd(&s_num[ch], w * v0);
            #pragma unroll
            for (int r = 1; r < RNK; ++r) {
                float v = f[r * NA];
                if (!finitef(v)) v = 0.f;
                atomicAdd(&s_num[r * NCH + ch], w * v);
            }
        } else atomicAdd(&s_nanw[ch], w);
    }
    #pragma unroll
    for (int off = 32; off; off >>= 1) tw += __shfl_down(tw, off);
    if ((tid & 63) == 0) atomicAdd(&s_total, tw);
    __syncthreads();
    for (int i = tid; i < RNK * NCH; i += 256)
        if (s_num[i] != 0.f) atomicAdd(&ws[FB_NUM + i], s_num[i]);
    for (int i = tid; i < NCH; i += 256)
        if (s_nanw[i] != 0.f) atomicAdd(&ws[FB_NANW + i], s_nanw[i]);
    if (tid == 0) atomicAdd(&ws[FB_TOT], s_total);
}
__global__ void fb_min_kernel(const float* data, int nnz, unsigned* minw) {
    float m = FLT_BIG;
    for (int i = blockIdx.x * blockDim.x + threadIdx.x; i < nnz;
         i += gridDim.x * blockDim.x) m = fminf(m, data[i]);
    #pragma unroll
    for (int off = 32; off; off >>= 1) m = fminf(m, __shfl_down(m, off));
    if ((threadIdx.x & 63) == 0) atomicMin(minw, fenc(m));
}
__global__ void fb_finalize_kernel(const float* ws, float* out) {
    int i = blockIdx.x * blockDim.x + threadIdx.x;
    if (i < RNK * NCH) {
        int c = i % NCH;
        float cnt = ws[FB_TOT] - ws[FB_NANW + c];
        out[i] = ws[FB_NUM + i] / cnt;
    }
}
__global__ __launch_bounds__(256) void fb_assign_kernel(
    const int* rows, const float* data, const unsigned* minw,
    float* out, int n, int per)
{
    const int spike = blockIdx.x * 256 + threadIdx.x;
    if (spike >= n) return;
    const float offset = fdec(*minw) - 1.0f;
    const float* d  = data + (size_t)spike * per;
    const int*   rr = rows + (size_t)spike * per;
    float bs = -FLT_BIG;
    int br = 0x7FFFFFFF;
    for (int j = 0; j < per; ++j) {
        float s = d[j] - offset;
        int r = rr[j];
        if (s > bs) { bs = s; br = r; }
        else if (s == bs && r < br) br = r;
    }
    out[RNK * NCH + spike] = (float)br;
}

// ================= host ======================================================
extern "C" void kernel_launch(void* const* d_in, const int* in_sizes, int n_in,
                              void* d_out, int out_size, void* d_ws, size_t ws_size,
                              hipStream_t stream) {
    const float* feats    = (const float*)d_in[0];
    const int*   channels = (const int*)d_in[1];
    const float* weights  = (const float*)d_in[2];
    const int*   lik_rows = (const int*)d_in[3];
    const float* lik_data = (const float*)d_in[5];

    int n   = in_sizes[2];
    int nnz = in_sizes[3];
    int per = nnz / n;

    float*    out = (float*)d_out;
    unsigned* wsu = (unsigned*)d_ws;
    float*    wsf = (float*)d_ws;

    const size_t req_bytes = (size_t)WS_WORDS * 4;
    // per-(bucket,rep) sub-list overflow margin (avg fill ~21 of 128)
    const bool cap_ok = (n <= NSTART * NREP * CAPR / 4);

    if (ws_size >= req_bytes && cap_ok) {
        k_init<<<GRID, 256, 0, stream>>>(lik_data, nnz, wsu, wsf);
        k_prep<<<GRID, 256, 0, stream>>>(channels, weights, n, wsu, wsf);
        k_accum<<<NSTART * 4, 256, 0, stream>>>(feats, wsu, wsf);
        k_final<<<GRID, 256, 0, stream>>>(lik_rows, lik_data, wsf, out, n, per);
    } else {
        fb_init_kernel<<<(FB_WORDS + 255) / 256, 256, 0, stream>>>(wsu);
        fb_accum_kernel<<<1024, 256, 0, stream>>>(feats, channels, weights, wsf, n);
        fb_finalize_kernel<<<(RNK * NCH + 255) / 256, 256, 0, stream>>>(wsf, out);
        fb_min_kernel<<<256, 256, 0, stream>>>(lik_data, nnz, wsu + FB_MIN);
        fb_assign_kernel<<<(n + 255) / 256, 256, 0, stream>>>(
            lik_rows, lik_data, wsu + FB_MIN, out, n, per);
    }
}

// Round 13
// 41.058 us; speedup vs baseline: 1.3049x; 1.0330x over previous
//
#include <hip/hip_runtime.h>
#include <math.h>

#define NCH 384
#define RNK 5
#define NA  32
#define NSTART 384            // starts < NCH-NA+1 = 353; 384 bins for safety
#define NREP 8                // counter/sub-list replicas per bucket
#define CAPR 128              // slots per (bucket, replica) sub-list
#define CAP (NREP*CAPR)       // 1024 slots per bucket
#define GRID 1536             // 6 blocks/CU x 256 CU
#define NTILES (NSTART*4)     // 4 tiles per bucket (accum block eats 2 sub-lists)
#define ASSIGN_GRID 256       // appended to accum grid: 1 spike per thread
#define EMP_GRID ((RNK*NCH + 3) / 4)   // 480 blocks: 1 wave per output elem
#define TILE_W 192            // 160 numerator + 32 nan-weight partials
#define FLT_BIG 3.402823466e38f

// ---- ws word layout ----
#define WS_CUR   0                           // NSTART*NREP u32 fill counters
#define WS_TOTP  (WS_CUR + NSTART*NREP)      // GRID f32 partial totals
#define WS_MINP  (WS_TOTP + GRID)            // GRID f32 partial mins
#define WS_ORDER (WS_MINP + GRID)            // NSTART*CAP uint2 (spike, weight)
#define WS_TILE  (WS_ORDER + NSTART*CAP*2)   // NTILES*TILE_W f32
#define WS_WORDS (WS_TILE + NTILES*TILE_W)

__device__ __forceinline__ bool finitef(float v) {
    return fabsf(v) <= FLT_BIG;   // NaN fails, +-inf exceeds
}

// ---- k1: zero counters + lik-min partials (no cg::grid.sync: R9 measured
// ~150us/sync on MI355X; stream ordering is the barrier) ----
__global__ __launch_bounds__(256) void k_init(
    const float* __restrict__ lik_data, int nnz,
    unsigned* __restrict__ wsu, float* __restrict__ wsf)
{
    const int tid = threadIdx.x, bid = blockIdx.x;
    const int lane = tid & 63, wave = tid >> 6;
    int i = bid * 256 + tid;
    if (i < NSTART * NREP) wsu[WS_CUR + i] = 0u;

    float m = FLT_BIG;
    const int G = GRID * 256;
    const int n4 = nnz >> 2;
    const float4* d4 = (const float4*)lik_data;
    for (int j = bid * 256 + tid; j < n4; j += G) {
        float4 v = d4[j];
        m = fminf(m, fminf(fminf(v.x, v.y), fminf(v.z, v.w)));
    }
    for (int j = (n4 << 2) + bid * 256 + tid; j < nnz; j += G)
        m = fminf(m, lik_data[j]);

    #pragma unroll
    for (int o = 32; o; o >>= 1) m = fminf(m, __shfl_down(m, o));
    __shared__ float sm[4];
    if (lane == 0) sm[wave] = m;
    __syncthreads();
    if (tid == 0)      // plain store to private slot — no funnel
        wsf[WS_MINP + bid] = fminf(fminf(sm[0], sm[1]), fminf(sm[2], sm[3]));
}

// ---- k2: replicated bucket scatter (packed spike+weight) + weight totals ----
__global__ __launch_bounds__(256) void k_prep(
    const int* __restrict__ channels, const float* __restrict__ weights,
    int n, unsigned* __restrict__ wsu, float* __restrict__ wsf)
{
    const int tid = threadIdx.x, bid = blockIdx.x;
    const int lane = tid & 63, wave = tid >> 6;
    const int rep = bid & (NREP - 1);
    const int G = GRID * 256;
    uint2* order = (uint2*)(wsu + WS_ORDER);

    float tw = 0.f;
    for (int sp = bid * 256 + tid; sp < n; sp += G) {
        const int st = channels[(size_t)sp * NA];   // channels[sp][0] == start
        const float wv = weights[sp];
        unsigned pos = atomicAdd(&wsu[WS_CUR + st * NREP + rep], 1u);
        if (pos < CAPR)   // pack weight with index: kills accum's dependent load
            order[(size_t)st * CAP + rep * CAPR + pos] =
                make_uint2((unsigned)sp, __float_as_uint(wv));
        tw += wv;
    }

    #pragma unroll
    for (int o = 32; o; o >>= 1) tw += __shfl_down(tw, o);
    __shared__ float st4[4];
    if (lane == 0) st4[wave] = tw;
    __syncthreads();
    if (tid == 0)      // plain store to private slot — no funnel
        wsf[WS_TOTP + bid] = st4[0] + st4[1] + st4[2] + st4[3];
}

// ---- k3: bucketed accumulation -> private partial tiles, PLUS appended
// assignment blocks (bid >= NTILES): assignments depend only on k1's min
// partials, so their streaming loads overlap accum's latency-bound gather ----
__global__ __launch_bounds__(256) void k_accum(
    const float* __restrict__ feats, const unsigned* __restrict__ wsu,
    float* __restrict__ wsf,
    const int* __restrict__ lik_rows, const float* __restrict__ lik_data,
    float* __restrict__ out, int n, int per)
{
    __shared__ float s_tile[TILE_W];
    __shared__ float sm[4];
    const int bid = blockIdx.x, tid = threadIdx.x;
    const int lane = tid & 63, wave = tid >> 6;

    if (bid >= NTILES) {
        // ---- assignment path ----
        const int abid = bid - NTILES;
        float m = FLT_BIG;
        for (int i = tid; i < GRID; i += 256) m = fminf(m, wsf[WS_MINP + i]);
        #pragma unroll
        for (int o = 32; o; o >>= 1) m = fminf(m, __shfl_down(m, o));
        if (lane == 0) sm[wave] = m;
        __syncthreads();
        const float offset =
            fminf(fminf(sm[0], sm[1]), fminf(sm[2], sm[3])) - 1.0f;

        const int G = ASSIGN_GRID * 256;
        for (int sp = abid * 256 + tid; sp < n; sp += G) {
            const float* d  = lik_data + (size_t)sp * per;
            const int*   rr = lik_rows + (size_t)sp * per;
            float bs = -FLT_BIG;
            int br = 0x7FFFFFFF;
            for (int j = 0; j < per; ++j) {
                float s = d[j] - offset;   // same f32 op as reference's shifted
                int r = rr[j];
                if (s > bs) { bs = s; br = r; }
                else if (s == bs && r < br) br = r;
            }
            out[RNK * NCH + sp] = (float)br;
        }
        return;
    }

    // ---- accum path: bucket b = bid>>2, tile tj = bid&3, sub-lists 2tj,2tj+1.
    // lane owns tile elems {lane, lane+64} (+ lane+128 for lane<32); e=r*32+a.
    const int b = bid >> 2, tj = bid & 3;

    for (int i = tid; i < TILE_W; i += 256) s_tile[i] = 0.f;
    __syncthreads();

    float acc0 = 0.f, acc1 = 0.f, acc2 = 0.f, nanw = 0.f;
    #pragma unroll
    for (int seg = 0; seg < 2; ++seg) {
        const int rep = tj * 2 + seg;
        int cnt = (int)wsu[WS_CUR + b * NREP + rep];
        if (cnt > CAPR) cnt = CAPR;
        const uint2* order =
            (const uint2*)(wsu + WS_ORDER) + (size_t)b * CAP + rep * CAPR;
        uint2 e = make_uint2(0u, 0u);
        if (wave < cnt) e = order[wave];
        for (int k = wave; k < cnt; k += 4) {
            const int spike = (int)e.x;
            const float w = __uint_as_float(e.y);
            const float* f = feats + (size_t)spike * (RNK * NA);
            uint2 ne = make_uint2(0u, 0u);
            if (k + 4 < cnt) ne = order[k + 4];   // prefetch next entry (8B)
            const float v0 = f[lane];          // elems [0,64)   ranks 0-1
            const float v1 = f[lane + 64];     // elems [64,128) ranks 2-3
            const float v2 = (lane < 32) ? f[lane + 128] : 0.f;  // rank 4
            const float r0 = __shfl(v0, lane & 31);  // rank-0 of column a
            if (finitef(r0)) {
                acc0 += w * (finitef(v0) ? v0 : 0.f);
                acc1 += w * (finitef(v1) ? v1 : 0.f);
                if (lane < 32) acc2 += w * (finitef(v2) ? v2 : 0.f);
            } else if (lane < 32) {
                nanw += w;
            }
            e = ne;
        }
    }

    atomicAdd(&s_tile[lane], acc0);
    atomicAdd(&s_tile[64 + lane], acc1);
    if (lane < 32) {
        atomicAdd(&s_tile[128 + lane], acc2);
        atomicAdd(&s_tile[160 + lane], nanw);
    }
    __syncthreads();

    float* dst = wsf + WS_TILE + (size_t)bid * TILE_W;  // private: plain stores
    for (int i = tid; i < TILE_W; i += 256) dst[i] = s_tile[i];
}

// ---- k4: tot fold + emp_mean gather (tiny: 480 blocks) ----
__global__ __launch_bounds__(256) void k_final(
    float* __restrict__ wsf, float* __restrict__ out)
{
    const int tid = threadIdx.x, bid = blockIdx.x;
    const int lane = tid & 63, wave = tid >> 6;

    float t = 0.f;
    for (int i = tid; i < GRID; i += 256) t += wsf[WS_TOTP + i];
    #pragma unroll
    for (int o = 32; o; o >>= 1) t += __shfl_down(t, o);
    __shared__ float st4[4];
    if (lane == 0) st4[wave] = t;
    __syncthreads();
    const float tot = st4[0] + st4[1] + st4[2] + st4[3];

    // one wave per output element; lanes split (db, tile-half of 4 slots)
    const int wg = bid * 4 + wave;
    if (wg < RNK * NCH) {
        const int c = wg % NCH, r = wg / NCH;
        const int db = lane & 31, half = lane >> 5;
        float s = 0.f, nb = 0.f;
        const int b = c - db;
        if (b >= 0) {
            #pragma unroll
            for (int jj = 0; jj < 2; ++jj) {
                const float* tp =
                    wsf + WS_TILE + ((size_t)b * 4 + jj * 2 + half) * TILE_W;
                s  += tp[r * 32 + db];
                nb += tp[160 + db];
            }
        }
        #pragma unroll
        for (int o = 32; o; o >>= 1) {
            s  += __shfl_down(s, o);
            nb += __shfl_down(nb, o);
        }
        if (lane == 0) out[wg] = s / (tot - nb);
    }
}

// ================= minimal-ws fallback (verified R2 lineage) ================
#define FB_NUM   0
#define FB_NANW  (RNK*NCH)
#define FB_TOT   (FB_NANW + NCH)
#define FB_MIN   (FB_TOT + 1)
#define FB_WORDS (FB_MIN + 1)

__device__ __forceinline__ unsigned fenc(float f) {
    unsigned u = __float_as_uint(f);
    return (u & 0x80000000u) ? ~u : (u | 0x80000000u);
}
__device__ __forceinline__ float fdec(unsigned u) {
    unsigned b = (u & 0x80000000u) ? (u ^ 0x80000000u) : ~u;
    return __uint_as_float(b);
}
__global__ void fb_init_kernel(unsigned* ws) {
    int i = blockIdx.x * blockDim.x + threadIdx.x;
    if (i < FB_WORDS) ws[i] = (i == FB_MIN) ? 0xFFFFFFFFu : 0u;
}
__global__ __launch_bounds__(256) void fb_accum_kernel(
    const float* feats, const int* channels, const float* weights,
    float* ws, int n)
{
    __shared__ float s_num[RNK * NCH];
    __shared__ float s_nanw[NCH];
    __shared__ float s_total;
    const int tid = threadIdx.x;
    for (int i = tid; i < RNK * NCH; i += 256) s_num[i] = 0.f;
    for (int i = tid; i < NCH; i += 256) s_nanw[i] = 0.f;
    if (tid == 0) s_total = 0.f;
    __syncthreads();
    const int total = n * NA;
    const int stride = gridDim.x * blockDim.x;
    float tw = 0.f;
    for (int idx = blockIdx.x * blockDim.x + tid; idx < total; idx += stride) {
        const int spike = idx >> 5, a = idx & (NA - 1);
        const int ch = channels[idx];
        const float w = weights[spike];
        if (a == 0) tw += w;
        const float* f = feats + (size_t)spike * (RNK * NA) + a;
        const float v0 = f[0];
        if (finitef(v0)) {
            atomicAdd(&s_num[ch], w * v0);
            #pragma unroll
            for (int r = 1; r < RNK; ++r) {
                float v = f[r * NA];
                if (!finitef(v)) v = 0.f;
                atomicAdd(&s_num[r * NCH + ch], w * v);
            }
        } else atomicAdd(&s_nanw[ch], w);
    }
    #pragma unroll
    for (int off = 32; off; off >>= 1) tw += __shfl_down(tw, off);
    if ((tid & 63) == 0) atomicAdd(&s_total, tw);
    __syncthreads();
    for (int i = tid; i < RNK * NCH; i += 256)
        if (s_num[i] != 0.f) atomicAdd(&ws[FB_NUM + i], s_num[i]);
    for (int i = tid; i < NCH; i += 256)
        if (s_nanw[i] != 0.f) atomicAdd(&ws[FB_NANW + i], s_nanw[i]);
    if (tid == 0) atomicAdd(&ws[FB_TOT], s_total);
}
__global__ void fb_min_kernel(const float* data, int nnz, unsigned* minw) {
    float m = FLT_BIG;
    for (int i = blockIdx.x * blockDim.x + threadIdx.x; i < nnz;
         i += gridDim.x * blockDim.x) m = fminf(m, data[i]);
    #pragma unroll
    for (int off = 32; off; off >>= 1) m = fminf(m, __shfl_down(m, off));
    if ((threadIdx.x & 63) == 0) atomicMin(minw, fenc(m));
}
__global__ void fb_finalize_kernel(const float* ws, float* out) {
    int i = blockIdx.x * blockDim.x + threadIdx.x;
    if (i < RNK * NCH) {
        int c = i % NCH;
        float cnt = ws[FB_TOT] - ws[FB_NANW + c];
        out[i] = ws[FB_NUM + i] / cnt;
    }
}
__global__ __launch_bounds__(256) void fb_assign_kernel(
    const int* rows, const float* data, const unsigned* minw,
    float* out, int n, int per)
{
    const int spike = blockIdx.x * 256 + threadIdx.x;
    if (spike >= n) return;
    const float offset = fdec(*minw) - 1.0f;
    const float* d  = data + (size_t)spike * per;
    const int*   rr = rows + (size_t)spike * per;
    float bs = -FLT_BIG;
    int br = 0x7FFFFFFF;
    for (int j = 0; j < per; ++j) {
        float s = d[j] - offset;
        int r = rr[j];
        if (s > bs) { bs = s; br = r; }
        else if (s == bs && r < br) br = r;
    }
    out[RNK * NCH + spike] = (float)br;
}

// ================= host ======================================================
extern "C" void kernel_launch(void* const* d_in, const int* in_sizes, int n_in,
                              void* d_out, int out_size, void* d_ws, size_t ws_size,
                              hipStream_t stream) {
    const float* feats    = (const float*)d_in[0];
    const int*   channels = (const int*)d_in[1];
    const float* weights  = (const float*)d_in[2];
    const int*   lik_rows = (const int*)d_in[3];
    const float* lik_data = (const float*)d_in[5];

    int n   = in_sizes[2];
    int nnz = in_sizes[3];
    int per = nnz / n;

    float*    out = (float*)d_out;
    unsigned* wsu = (unsigned*)d_ws;
    float*    wsf = (float*)d_ws;

    const size_t req_bytes = (size_t)WS_WORDS * 4;
    // per-(bucket,rep) sub-list overflow margin (avg fill ~21 of 128)
    const bool cap_ok = (n <= NSTART * NREP * CAPR / 4);

    if (ws_size >= req_bytes && cap_ok) {
        k_init<<<GRID, 256, 0, stream>>>(lik_data, nnz, wsu, wsf);
        k_prep<<<GRID, 256, 0, stream>>>(channels, weights, n, wsu, wsf);
        k_accum<<<NTILES + ASSIGN_GRID, 256, 0, stream>>>(
            feats, wsu, wsf, lik_rows, lik_data, out, n, per);
        k_final<<<EMP_GRID, 256, 0, stream>>>(wsf, out);
    } else {
        fb_init_kernel<<<(FB_WORDS + 255) / 256, 256, 0, stream>>>(wsu);
        fb_accum_kernel<<<1024, 256, 0, stream>>>(feats, channels, weights, wsf, n);
        fb_finalize_kernel<<<(RNK * NCH + 255) / 256, 256, 0, stream>>>(wsf, out);
        fb_min_kernel<<<256, 256, 0, stream>>>(lik_data, nnz, wsu + FB_MIN);
        fb_assign_kernel<<<(n + 255) / 256, 256, 0, stream>>>(
            lik_rows, lik_data, wsu + FB_MIN, out, n, per);
    }
}